// Round 2
// baseline (517.171 us; speedup 1.0000x reference)
//
#include <hip/hip_runtime.h>
#include <hip/hip_bf16.h>

// O[b,i,h,p] = sum_{c=l*3+j in 768, tap in 3} W[l,j,tap,i] * S_{b,h}[c][p+tap]
// S[c][t]: t=0,8,9 -> 0; t=(w+1)%7+1 <- V[c][w]
// V[c][w] = x[b,l,r1,w]*[0<=r1<7] + x[b,256+l,r2,w]*[0<=r2<7],
//   r1 = h+j-1, r2 = ((h+6)%7)+j-1            (verified rounds 1-2)
//
// Round 3: V precomputed into d_ws as Vt[bh][t][c] bf16 (77 MB).
// Round 5: gemm_vt was LDS-instruction-bound (127 LDS instrs/chunk/block,
// ~70% of CU cycles; MfmaUtil 31%). Rewrite:
//  - M packed: m = bh*7 + p (no dead p=7 rows, -12.5% MFMA). A-row for tap
//    is Vt row (m + tap - 1), zero-masked at p==0/tap==0 and p==6/tap==2.
//    A-fragments load DIRECTLY from global (L1/L2-resident, ~8KB/chunk/block)
//    -> kills the T tile, its staging, and 48 LDS reads per chunk.
//  - Bt staged LINEAR via global_load_lds (width 16) into a double buffer:
//    no ds_write instrs, 1 barrier/chunk, prefetch overlaps MFMA.

typedef __bf16 bf16x8 __attribute__((ext_vector_type(8)));
typedef float f32x4 __attribute__((ext_vector_type(4)));
typedef unsigned int u32;

#define VT_OFFSET (4u << 20)                       // W2 at d_ws+0, Vt at d_ws+4MB
#define VT_BYTES  (7168ull * 7 * 768 * 2)          // 77,070,336
#define WS_NEED   (VT_OFFSET + VT_BYTES)

__device__ __forceinline__ void gload_lds16(const void* g, void* l) {
    __builtin_amdgcn_global_load_lds(
        (const __attribute__((address_space(1))) u32*)g,
        (__attribute__((address_space(3))) u32*)l, 16, 0, 0);
}

__global__ __launch_bounds__(256) void prep_w(const float* __restrict__ Wg,
                                              __bf16* __restrict__ W2) {
    int idx = blockIdx.x * 256 + threadIdx.x;      // over 512*2304
    int i = idx / 2304;
    int kk = idx - i * 2304;
    int tap = kk / 768;
    int c = kk - tap * 768;
    W2[idx] = (__bf16)Wg[(c * 3 + tap) * 512 + i];
}

// Block per (b, g) with g = channel-half (l = g*128 .. g*128+127).
__global__ __launch_bounds__(256) void prep_v(const float* __restrict__ x,
                                              __bf16* __restrict__ Vt) {
    __shared__ float xs[256 * 49];                 // rows 0..127 grp a, 128..255 grp b
    const int b = blockIdx.x >> 1;
    const int g = blockIdx.x & 1;
    const int tid = threadIdx.x;

    {
        const float4* src0 = (const float4*)(x + ((size_t)b * 512 + g * 128) * 49);
        const float4* src1 = (const float4*)(x + ((size_t)b * 512 + 256 + g * 128) * 49);
        float4* dst0 = (float4*)xs;
        float4* dst1 = (float4*)(xs + 128 * 49);
        #pragma unroll
        for (int it = 0; it < 7; ++it) {
            const int q = it * 256 + tid;
            if (q < 1568) dst0[q] = src0[q];
        }
        #pragma unroll
        for (int it = 0; it < 7; ++it) {
            const int q = it * 256 + tid;
            if (q < 1568) dst1[q] = src1[q];
        }
    }
    __syncthreads();

    for (int h = 0; h < 7; ++h) {
        const int hm = (h + 6) % 7;
        for (int it = 0; it < 2; ++it) {
            const int u = it * 256 + tid;
            if (u < 336) {
                const int r = u / 48;              // 0..6  (Vt row within h)
                const int k = u - r * 48;          // 0..47 (16B unit within row-half)
                const int w = (r + 6) % 7;         // r = (w+1)%7
                bf16x8 vv;
                #pragma unroll
                for (int e = 0; e < 8; ++e) {
                    const int c = k * 8 + e;       // local c in 0..383
                    const int l = c / 3;
                    const int j = c - 3 * l;
                    const int r1 = h + j - 1;
                    const int r2 = hm + j - 1;
                    float v = 0.f;
                    if (r1 >= 0 && r1 < 7) v += xs[l * 49 + r1 * 7 + w];
                    if (r2 >= 0 && r2 < 7) v += xs[(128 + l) * 49 + r2 * 7 + w];
                    vv[e] = (__bf16)v;
                }
                *(bf16x8*)(Vt + (size_t)((b * 7 + h) * 7 + r) * 768 + g * 384 + k * 8) = vv;
            }
        }
    }
}

// Packed-M GEMM: M = 50176 (m = bh*7+p), N = 512, K = 2304 (24 chunks x 32c x 3tap).
// Grid 392 mb x 4 nb, XCD-swizzled. Block tile 128(M) x 128(N), 4 waves 2x2.
__global__ __launch_bounds__(256) void gemm_vt(const __bf16* __restrict__ Vt,
                                               const __bf16* __restrict__ W2,
                                               float* __restrict__ out) {
    __shared__ __bf16 Bt[2][12288];      // linear: bf16 idx = tap*4096 + n*32 + q*8

    const int tid = threadIdx.x;
    // XCD swizzle: 4 N-siblings of one mb land on the same XCD
    const int g0 = blockIdx.x;
    const int nb = (g0 >> 3) & 3;
    const int mb = ((g0 >> 5) << 3) | (g0 & 7);    // 0..391 (grid 1568 = 49*32)
    const int i0 = nb * 128;

    const int lane = tid & 63;
    const int wave = tid >> 6;
    const int wm = wave >> 1;            // 2x2 wave grid, each 64x64
    const int wn = wave & 1;
    const int ln15 = lane & 15;
    const int gq = lane >> 4;

    // ---- Bt stage source byte-offsets (6 units of 16B per thread) ----
    int soff[6];
    #pragma unroll
    for (int it = 0; it < 6; ++it) {
        const int u = it * 256 + tid;              // u = tap*512 + n*4 + q
        const int tap = u >> 9;
        const int rem = u & 511;
        const int n = rem >> 2;
        const int q = rem & 3;
        soff[it] = ((i0 + n) * 2304 + tap * 768 + q * 8) * 2;
    }

    // ---- A-row byte-offsets + p (mod 7) masks, per mf ----
    int aoff[4], md7[4];
    #pragma unroll
    for (int mf = 0; mf < 4; ++mf) {
        const int m = mb * 128 + wm * 64 + mf * 16 + ln15;   // < 50176
        aoff[mf] = m * 1536 + gq * 16;             // bytes into Vt
        md7[mf] = m % 7;                           // p
    }

    bf16x8 zero8;
    #pragma unroll
    for (int e = 0; e < 8; ++e) zero8[e] = (__bf16)0.f;

    f32x4 acc[4][4];
    #pragma unroll
    for (int a = 0; a < 4; ++a)
        #pragma unroll
        for (int bq = 0; bq < 4; ++bq) acc[a][bq] = (f32x4){0.f, 0.f, 0.f, 0.f};

    const char* VtB = (const char*)Vt;
    const char* W2B = (const char*)W2;

    // ---- prologue: stage chunk 0 -> Bt[0] ----
    #pragma unroll
    for (int it = 0; it < 6; ++it)
        gload_lds16(W2B + soff[it], &Bt[0][it * 2048 + tid * 8]);
    __syncthreads();                     // drains vmcnt: chunk-0 Bt ready

    for (int chunk = 0; chunk < 24; ++chunk) {
        const int cur = chunk & 1;
        // ---- prefetch next Bt chunk (flies during MFMA phase) ----
        if (chunk < 23) {
            const int ck2 = (chunk + 1) * 64;
            #pragma unroll
            for (int it = 0; it < 6; ++it)
                gload_lds16(W2B + soff[it] + ck2,
                            &Bt[cur ^ 1][it * 2048 + tid * 8]);
        }
        const int ck = chunk * 64;

        #pragma unroll
        for (int tap = 0; tap < 3; ++tap) {
            bf16x8 af[4], bfr[4];
            #pragma unroll
            for (int mf = 0; mf < 4; ++mf) {
                af[mf] = zero8;
                bool ok;
                if (tap == 0)      ok = (md7[mf] != 0);
                else if (tap == 2) ok = (md7[mf] != 6);
                else               ok = true;
                if (ok)
                    af[mf] = *(const bf16x8*)(VtB + aoff[mf] + (tap - 1) * 1536 + ck);
            }
            #pragma unroll
            for (int nf = 0; nf < 4; ++nf) {
                const int n_l = wn * 64 + nf * 16 + ln15;
                bfr[nf] = *(const bf16x8*)(&Bt[cur][tap * 4096 + n_l * 32 + gq * 8]);
            }
            #pragma unroll
            for (int mf = 0; mf < 4; ++mf)
                #pragma unroll
                for (int nf = 0; nf < 4; ++nf)
                    acc[mf][nf] = __builtin_amdgcn_mfma_f32_16x16x32_bf16(
                        af[mf], bfr[nf], acc[mf][nf], 0, 0, 0);
        }

        __syncthreads();                 // waves done with Bt[cur]; prefetch landed
    }

    // ---- epilogue: D row = gq*4+reg (packed m), col = lane&15 ----
    #pragma unroll
    for (int mf = 0; mf < 4; ++mf) {
        #pragma unroll
        for (int r = 0; r < 4; ++r) {
            const int m = mb * 128 + wm * 64 + mf * 16 + gq * 4 + r;
            const int bh = m / 7;
            const int p = m - 7 * bh;
            const int b = bh / 7;
            const int h = bh - 7 * b;
            #pragma unroll
            for (int nf = 0; nf < 4; ++nf) {
                const int i = i0 + wn * 64 + nf * 16 + ln15;
                out[(((size_t)b * 512 + i) * 7 + h) * 7 + p] = acc[mf][nf][r];
            }
        }
    }
}

// ---------------- fallback (round-2 implicit staging) if ws is small --------
__global__ __launch_bounds__(256) void gemm_shift(const float* __restrict__ x,
                                                  const __bf16* __restrict__ W2,
                                                  float* __restrict__ out) {
    __shared__ __bf16 T[16 * 10 * 40];
    __shared__ __bf16 Bt[128 * 104];

    const int tid = threadIdx.x;
    const int mb = blockIdx.x >> 2;
    const int nb = blockIdx.x & 3;
    const int i0 = nb * 128;

    const int cl  = tid & 31;
    const int bh0 = tid >> 5;
    const int bhg0 = mb * 16 + bh0;
    const int bhg1 = bhg0 + 8;
    const int b0 = bhg0 / 7, h0 = bhg0 - 7 * b0;
    const int b1 = bhg1 / 7, h1 = bhg1 - 7 * b1;
    const int hm0 = (h0 + 6) % 7, hm1 = (h1 + 6) % 7;

    for (int q = tid; q < 16 * 10 * 40 / 2; q += 256) ((int*)T)[q] = 0;

    const int lane = tid & 63;
    const int wave = tid >> 6;
    const int wm = wave >> 1;
    const int wn = wave & 1;
    const int ln15 = lane & 15;
    const int gq = lane >> 4;

    f32x4 acc[4][4];
    #pragma unroll
    for (int a = 0; a < 4; ++a)
        #pragma unroll
        for (int bq = 0; bq < 4; ++bq) acc[a][bq] = (f32x4){0.f, 0.f, 0.f, 0.f};

    __syncthreads();

    for (int chunk = 0; chunk < 24; ++chunk) {
        const int cg = chunk * 32 + cl;
        const int l = cg / 3;
        const int j = cg - 3 * l;
        {
            const int r1 = h0 + j - 1, r2 = hm0 + j - 1;
            float v[7] = {0.f, 0.f, 0.f, 0.f, 0.f, 0.f, 0.f};
            if (r1 >= 0 && r1 < 7) {
                const float* p1 = x + (((size_t)b0 * 512 + l) * 7 + r1) * 7;
                #pragma unroll
                for (int w = 0; w < 7; ++w) v[w] += p1[w];
            }
            if (r2 >= 0 && r2 < 7) {
                const float* p2 = x + (((size_t)b0 * 512 + 256 + l) * 7 + r2) * 7;
                #pragma unroll
                for (int w = 0; w < 7; ++w) v[w] += p2[w];
            }
            #pragma unroll
            for (int w = 0; w < 7; ++w)
                T[bh0 * 400 + ((w + 1) % 7 + 1) * 40 + cl] = (__bf16)v[w];
        }
        {
            const int r1 = h1 + j - 1, r2 = hm1 + j - 1;
            float v[7] = {0.f, 0.f, 0.f, 0.f, 0.f, 0.f, 0.f};
            if (r1 >= 0 && r1 < 7) {
                const float* p1 = x + (((size_t)b1 * 512 + l) * 7 + r1) * 7;
                #pragma unroll
                for (int w = 0; w < 7; ++w) v[w] += p1[w];
            }
            if (r2 >= 0 && r2 < 7) {
                const float* p2 = x + (((size_t)b1 * 512 + 256 + l) * 7 + r2) * 7;
                #pragma unroll
                for (int w = 0; w < 7; ++w) v[w] += p2[w];
            }
            #pragma unroll
            for (int w = 0; w < 7; ++w)
                T[(bh0 + 8) * 400 + ((w + 1) % 7 + 1) * 40 + cl] = (__bf16)v[w];
        }

        #pragma unroll
        for (int it = 0; it < 6; ++it) {
            const int u = it * 256 + tid;
            const int tap = u >> 9;
            const int rem = u & 511;
            const int n = rem >> 2;
            const int q = rem & 3;
            const float4 val = *(const float4*)(W2 + (size_t)(i0 + n) * 2304 +
                                                tap * 768 + chunk * 32 + q * 8);
            *(float4*)(&Bt[n * 104 + tap * 32 + q * 8]) = val;
        }

        __syncthreads();

        #pragma unroll
        for (int tap = 0; tap < 3; ++tap) {
            bf16x8 af[4], bfr[4];
            #pragma unroll
            for (int mf = 0; mf < 4; ++mf) {
                const int bh_l = wm * 8 + mf * 2 + (ln15 >> 3);
                const int p = ln15 & 7;
                af[mf] = *(const bf16x8*)(&T[(bh_l * 10 + p + tap) * 40 + gq * 8]);
            }
            #pragma unroll
            for (int nf = 0; nf < 4; ++nf) {
                const int n_l = wn * 64 + nf * 16 + ln15;
                bfr[nf] = *(const bf16x8*)(&Bt[n_l * 104 + tap * 32 + gq * 8]);
            }
            #pragma unroll
            for (int mf = 0; mf < 4; ++mf)
                #pragma unroll
                for (int nf = 0; nf < 4; ++nf)
                    acc[mf][nf] = __builtin_amdgcn_mfma_f32_16x16x32_bf16(
                        af[mf], bfr[nf], acc[mf][nf], 0, 0, 0);
        }

        __syncthreads();
    }

    #pragma unroll
    for (int mf = 0; mf < 4; ++mf) {
        #pragma unroll
        for (int r = 0; r < 4; ++r) {
            const int mrow = gq * 4 + r;
            const int Mg_l = wm * 64 + mf * 16 + mrow;
            const int p = Mg_l & 7;
            if (p == 7) continue;
            const int bh_l = Mg_l >> 3;
            const int bhg = mb * 16 + bh_l;
            const int b = bhg / 7;
            const int h = bhg - 7 * b;
            #pragma unroll
            for (int nf = 0; nf < 4; ++nf) {
                const int i = i0 + wn * 64 + nf * 16 + ln15;
                out[(((size_t)b * 512 + i) * 7 + h) * 7 + p] = acc[mf][nf][r];
            }
        }
    }
}

extern "C" void kernel_launch(void* const* d_in, const int* in_sizes, int n_in,
                              void* d_out, int out_size, void* d_ws, size_t ws_size,
                              hipStream_t stream) {
    const float* x  = (const float*)d_in[0];   // (1024,512,7,7) fp32
    const float* Wg = (const float*)d_in[1];   // (256,3,3,512) fp32
    float* out = (float*)d_out;                // (1024,512,7,7) fp32
    __bf16* W2 = (__bf16*)d_ws;                // 512*2304 bf16 = 2.36 MB

    prep_w<<<dim3(512 * 2304 / 256), dim3(256), 0, stream>>>(Wg, W2);

    if (ws_size >= WS_NEED) {
        __bf16* Vt = (__bf16*)((char*)d_ws + VT_OFFSET);
        prep_v<<<dim3(2048), dim3(256), 0, stream>>>(x, Vt);
        gemm_vt<<<dim3(392 * 4), dim3(256), 0, stream>>>(Vt, W2, out);
    } else {
        gemm_shift<<<dim3(448 * 4), dim3(256), 0, stream>>>(x, W2, out);
    }
}

// Round 3
// 388.897 us; speedup vs baseline: 1.3298x; 1.3298x over previous
//
#include <hip/hip_runtime.h>
#include <hip/hip_bf16.h>

// O[b,i,h,p] = sum_{c=l*3+j in 768, tap in 3} W[l,j,tap,i] * S_{b,h}[c][p+tap]
// S[c][t]: t=0,8,9 -> 0; t=(w+1)%7+1 <- V[c][w]
// V[c][w] = x[b,l,r1,w]*[0<=r1<7] + x[b,256+l,r2,w]*[0<=r2<7],
//   r1 = h+j-1, r2 = ((h+6)%7)+j-1            (verified rounds 1-2)
//
// Round 3: V precomputed into d_ws as Vt[bh][t][c] bf16 (77 MB).
// Round 4: prep_v rewritten (LDS-staged, coalesced) — ~25 us.
// Round 5: A-direct-from-global GEMM — REFUTED (1536B lane stride, 187->315us).
// Round 6: gemm_vt reverted to round-4 version (187 us known-good).
//          prep_w was the hidden ~150 us: 6144-B-stride scalar reads, 16x
//          L2-thrashed re-fetch (~75 MB scattered). Rewritten as tiled LDS
//          transpose: 96kk x 64i tiles, coalesced float4 reads (source read
//          once), full-line bf16x8 writes.

typedef __bf16 bf16x8 __attribute__((ext_vector_type(8)));
typedef float f32x4 __attribute__((ext_vector_type(4)));

#define VT_OFFSET (4u << 20)                       // W2 at d_ws+0, Vt at d_ws+4MB
#define VT_BYTES  (7168ull * 7 * 768 * 2)          // 77,070,336
#define WS_NEED   (VT_OFFSET + VT_BYTES)

// ---- prep_w: Wg[(c*3+tap)*512 + i] -> W2[i*2304 + tap*768 + c] ----
// Tile: 96 kk-rows (= 3 taps x 32 c) x 64 i. Grid 24 x 8 = 192 blocks.
__global__ __launch_bounds__(256) void prep_w(const float* __restrict__ Wg,
                                              __bf16* __restrict__ W2) {
    __shared__ float ws_[96][65];                  // +1 pad
    const int kt = blockIdx.x % 24;                // kk-tile
    const int it_ = blockIdx.x / 24;               // i-tile
    const int K0 = kt * 96;                        // kk base (= 3 * 32*kt)
    const int I0 = it_ * 64;                       // i base
    const int tid = threadIdx.x;

    // read: 96 rows x 16 float4 = 1536 units, 6/thread, coalesced in i
    #pragma unroll
    for (int t = 0; t < 6; ++t) {
        const int u = t * 256 + tid;
        const int row = u >> 4;                    // 0..95
        const int f4 = u & 15;                     // 0..15
        const float4 v = *(const float4*)(Wg + (size_t)(K0 + row) * 512 + I0 + f4 * 4);
        ws_[row][f4 * 4 + 0] = v.x;
        ws_[row][f4 * 4 + 1] = v.y;
        ws_[row][f4 * 4 + 2] = v.z;
        ws_[row][f4 * 4 + 3] = v.w;
    }
    __syncthreads();

    // write: 64 i x 3 tap x 4 q units of 8 bf16 = 768 units, 3/thread.
    // dest W2[(I0+i)*2304 + tap*768 + 32*kt + q*8 .. +7] — full 64B lines.
    #pragma unroll
    for (int t = 0; t < 3; ++t) {
        const int u = t * 256 + tid;
        const int i = u / 12;
        const int rem = u - i * 12;
        const int tap = rem >> 2;
        const int q = rem & 3;
        bf16x8 o;
        #pragma unroll
        for (int e = 0; e < 8; ++e) {
            const int c_loc = q * 8 + e;           // 0..31
            o[e] = (__bf16)ws_[3 * c_loc + tap][i];
        }
        *(bf16x8*)(W2 + (size_t)(I0 + i) * 2304 + tap * 768 + 32 * kt + q * 8) = o;
    }
}

// Block per (b, g) with g = channel-half (l = g*128 .. g*128+127).
__global__ __launch_bounds__(256) void prep_v(const float* __restrict__ x,
                                              __bf16* __restrict__ Vt) {
    __shared__ float xs[256 * 49];                 // rows 0..127 grp a, 128..255 grp b
    const int b = blockIdx.x >> 1;
    const int g = blockIdx.x & 1;
    const int tid = threadIdx.x;

    {
        const float4* src0 = (const float4*)(x + ((size_t)b * 512 + g * 128) * 49);
        const float4* src1 = (const float4*)(x + ((size_t)b * 512 + 256 + g * 128) * 49);
        float4* dst0 = (float4*)xs;
        float4* dst1 = (float4*)(xs + 128 * 49);
        #pragma unroll
        for (int it = 0; it < 7; ++it) {
            const int q = it * 256 + tid;
            if (q < 1568) dst0[q] = src0[q];
        }
        #pragma unroll
        for (int it = 0; it < 7; ++it) {
            const int q = it * 256 + tid;
            if (q < 1568) dst1[q] = src1[q];
        }
    }
    __syncthreads();

    for (int h = 0; h < 7; ++h) {
        const int hm = (h + 6) % 7;
        for (int it = 0; it < 2; ++it) {
            const int u = it * 256 + tid;
            if (u < 336) {
                const int r = u / 48;              // 0..6  (Vt row within h)
                const int k = u - r * 48;          // 0..47 (16B unit within row-half)
                const int w = (r + 6) % 7;         // r = (w+1)%7
                bf16x8 vv;
                #pragma unroll
                for (int e = 0; e < 8; ++e) {
                    const int c = k * 8 + e;       // local c in 0..383
                    const int l = c / 3;
                    const int j = c - 3 * l;
                    const int r1 = h + j - 1;
                    const int r2 = hm + j - 1;
                    float v = 0.f;
                    if (r1 >= 0 && r1 < 7) v += xs[l * 49 + r1 * 7 + w];
                    if (r2 >= 0 && r2 < 7) v += xs[(128 + l) * 49 + r2 * 7 + w];
                    vv[e] = (__bf16)v;
                }
                *(bf16x8*)(Vt + (size_t)((b * 7 + h) * 7 + r) * 768 + g * 384 + k * 8) = vv;
            }
        }
    }
}

// ---- round-4 gemm_vt (verified, 187 us) ----
__global__ __launch_bounds__(256) void gemm_vt(const __bf16* __restrict__ Vt,
                                               const __bf16* __restrict__ W2,
                                               float* __restrict__ out) {
    __shared__ __bf16 T[16 * 400];       // [bh16][t10][c32], t-stride 40 bf16
    __shared__ __bf16 Bt[128 * 104];     // [n128][tap*32+c], row stride 104 bf16

    const int tid = threadIdx.x;
    // XCD swizzle: the 4 N-siblings of one mb are g, g+8, g+16, g+24 -> same XCD
    const int g0 = blockIdx.x;
    const int nb = (g0 >> 3) & 3;
    const int mb = ((g0 >> 5) << 3) | (g0 & 7);
    const int i0 = nb * 128;

    // zero T once (rows t=0,8,9 stay zero; rows 1..7 are re-staged per chunk)
    for (int q = tid; q < 3200; q += 256) ((int*)T)[q] = 0;

    const int lane = tid & 63;
    const int wave = tid >> 6;
    const int wm = wave >> 1;            // 2x2 wave grid, each 64x64
    const int wn = wave & 1;
    const int ln15 = lane & 15;
    const int gq = lane >> 4;

    f32x4 acc[4][4];
    #pragma unroll
    for (int a = 0; a < 4; ++a)
        #pragma unroll
        for (int bq = 0; bq < 4; ++bq) acc[a][bq] = (f32x4){0.f, 0.f, 0.f, 0.f};

    __syncthreads();                     // T zeroing complete before staging

    for (int chunk = 0; chunk < 24; ++chunk) {
        // ---- stage T: 448 16B units (16 bh x 7 t x 4 q), 2 iters ----
        #pragma unroll
        for (int it = 0; it < 2; ++it) {
            const int u = it * 256 + tid;
            if (u < 448) {
                const int q = u & 3;
                const int tmp = u >> 2;          // 0..111
                const int t = tmp % 7;
                const int bh = tmp / 7;
                const float4 val = *(const float4*)(
                    Vt + (size_t)((mb * 16 + bh) * 7 + t) * 768 + chunk * 32 + q * 8);
                *(float4*)(&T[bh * 400 + (t + 1) * 40 + q * 8]) = val;
            }
        }
        // ---- stage Bt: 1536 16B units, 6 per thread ----
        #pragma unroll
        for (int it = 0; it < 6; ++it) {
            const int u = it * 256 + tid;        // u = tap*512 + n*4 + q
            const int tap = u >> 9;
            const int rem = u & 511;
            const int n = rem >> 2;
            const int q = rem & 3;
            const float4 val = *(const float4*)(W2 + (size_t)(i0 + n) * 2304 +
                                                tap * 768 + chunk * 32 + q * 8);
            *(float4*)(&Bt[n * 104 + tap * 32 + q * 8]) = val;
        }

        __syncthreads();

        // ---- MFMA: 3 taps x (4 Mfrag x 4 Nfrag) per wave ----
        #pragma unroll
        for (int tap = 0; tap < 3; ++tap) {
            bf16x8 af[4], bfr[4];
            #pragma unroll
            for (int mf = 0; mf < 4; ++mf) {
                const int bh_l = wm * 8 + mf * 2 + (ln15 >> 3);
                const int p = ln15 & 7;
                af[mf] = *(const bf16x8*)(&T[(bh_l * 10 + p + tap) * 40 + gq * 8]);
            }
            #pragma unroll
            for (int nf = 0; nf < 4; ++nf) {
                const int n_l = wn * 64 + nf * 16 + ln15;
                bfr[nf] = *(const bf16x8*)(&Bt[n_l * 104 + tap * 32 + gq * 8]);
            }
            #pragma unroll
            for (int mf = 0; mf < 4; ++mf)
                #pragma unroll
                for (int nf = 0; nf < 4; ++nf)
                    acc[mf][nf] = __builtin_amdgcn_mfma_f32_16x16x32_bf16(
                        af[mf], bfr[nf], acc[mf][nf], 0, 0, 0);
        }

        __syncthreads();
    }

    // ---- epilogue: D row = quad*4+reg, col = lane&15 ----
    #pragma unroll
    for (int mf = 0; mf < 4; ++mf) {
        #pragma unroll
        for (int r = 0; r < 4; ++r) {
            const int mrow = gq * 4 + r;                 // 0..15
            const int Mg_l = wm * 64 + mf * 16 + mrow;
            const int p = Mg_l & 7;
            if (p == 7) continue;                        // padded row
            const int bh_l = Mg_l >> 3;
            const int bhg = mb * 16 + bh_l;
            const int b = bhg / 7;
            const int h = bhg - 7 * b;
            #pragma unroll
            for (int nf = 0; nf < 4; ++nf) {
                const int i = i0 + wn * 64 + nf * 16 + ln15;
                out[(((size_t)b * 512 + i) * 7 + h) * 7 + p] = acc[mf][nf][r];
            }
        }
    }
}

// ---------------- fallback (round-2 implicit staging) if ws is small --------
__global__ __launch_bounds__(256) void gemm_shift(const float* __restrict__ x,
                                                  const __bf16* __restrict__ W2,
                                                  float* __restrict__ out) {
    __shared__ __bf16 T[16 * 10 * 40];
    __shared__ __bf16 Bt[128 * 104];

    const int tid = threadIdx.x;
    const int mb = blockIdx.x >> 2;
    const int nb = blockIdx.x & 3;
    const int i0 = nb * 128;

    const int cl  = tid & 31;
    const int bh0 = tid >> 5;
    const int bhg0 = mb * 16 + bh0;
    const int bhg1 = bhg0 + 8;
    const int b0 = bhg0 / 7, h0 = bhg0 - 7 * b0;
    const int b1 = bhg1 / 7, h1 = bhg1 - 7 * b1;
    const int hm0 = (h0 + 6) % 7, hm1 = (h1 + 6) % 7;

    for (int q = tid; q < 16 * 10 * 40 / 2; q += 256) ((int*)T)[q] = 0;

    const int lane = tid & 63;
    const int wave = tid >> 6;
    const int wm = wave >> 1;
    const int wn = wave & 1;
    const int ln15 = lane & 15;
    const int gq = lane >> 4;

    f32x4 acc[4][4];
    #pragma unroll
    for (int a = 0; a < 4; ++a)
        #pragma unroll
        for (int bq = 0; bq < 4; ++bq) acc[a][bq] = (f32x4){0.f, 0.f, 0.f, 0.f};

    __syncthreads();

    for (int chunk = 0; chunk < 24; ++chunk) {
        const int cg = chunk * 32 + cl;
        const int l = cg / 3;
        const int j = cg - 3 * l;
        {
            const int r1 = h0 + j - 1, r2 = hm0 + j - 1;
            float v[7] = {0.f, 0.f, 0.f, 0.f, 0.f, 0.f, 0.f};
            if (r1 >= 0 && r1 < 7) {
                const float* p1 = x + (((size_t)b0 * 512 + l) * 7 + r1) * 7;
                #pragma unroll
                for (int w = 0; w < 7; ++w) v[w] += p1[w];
            }
            if (r2 >= 0 && r2 < 7) {
                const float* p2 = x + (((size_t)b0 * 512 + 256 + l) * 7 + r2) * 7;
                #pragma unroll
                for (int w = 0; w < 7; ++w) v[w] += p2[w];
            }
            #pragma unroll
            for (int w = 0; w < 7; ++w)
                T[bh0 * 400 + ((w + 1) % 7 + 1) * 40 + cl] = (__bf16)v[w];
        }
        {
            const int r1 = h1 + j - 1, r2 = hm1 + j - 1;
            float v[7] = {0.f, 0.f, 0.f, 0.f, 0.f, 0.f, 0.f};
            if (r1 >= 0 && r1 < 7) {
                const float* p1 = x + (((size_t)b1 * 512 + l) * 7 + r1) * 7;
                #pragma unroll
                for (int w = 0; w < 7; ++w) v[w] += p1[w];
            }
            if (r2 >= 0 && r2 < 7) {
                const float* p2 = x + (((size_t)b1 * 512 + 256 + l) * 7 + r2) * 7;
                #pragma unroll
                for (int w = 0; w < 7; ++w) v[w] += p2[w];
            }
            #pragma unroll
            for (int w = 0; w < 7; ++w)
                T[(bh0 + 8) * 400 + ((w + 1) % 7 + 1) * 40 + cl] = (__bf16)v[w];
        }

        #pragma unroll
        for (int it = 0; it < 6; ++it) {
            const int u = it * 256 + tid;
            const int tap = u >> 9;
            const int rem = u & 511;
            const int n = rem >> 2;
            const int q = rem & 3;
            const float4 val = *(const float4*)(W2 + (size_t)(i0 + n) * 2304 +
                                                tap * 768 + chunk * 32 + q * 8);
            *(float4*)(&Bt[n * 104 + tap * 32 + q * 8]) = val;
        }

        __syncthreads();

        #pragma unroll
        for (int tap = 0; tap < 3; ++tap) {
            bf16x8 af[4], bfr[4];
            #pragma unroll
            for (int mf = 0; mf < 4; ++mf) {
                const int bh_l = wm * 8 + mf * 2 + (ln15 >> 3);
                const int p = ln15 & 7;
                af[mf] = *(const bf16x8*)(&T[(bh_l * 10 + p + tap) * 40 + gq * 8]);
            }
            #pragma unroll
            for (int nf = 0; nf < 4; ++nf) {
                const int n_l = wn * 64 + nf * 16 + ln15;
                bfr[nf] = *(const bf16x8*)(&Bt[n_l * 104 + tap * 32 + gq * 8]);
            }
            #pragma unroll
            for (int mf = 0; mf < 4; ++mf)
                #pragma unroll
                for (int nf = 0; nf < 4; ++nf)
                    acc[mf][nf] = __builtin_amdgcn_mfma_f32_16x16x32_bf16(
                        af[mf], bfr[nf], acc[mf][nf], 0, 0, 0);
        }

        __syncthreads();
    }

    #pragma unroll
    for (int mf = 0; mf < 4; ++mf) {
        #pragma unroll
        for (int r = 0; r < 4; ++r) {
            const int mrow = gq * 4 + r;
            const int Mg_l = wm * 64 + mf * 16 + mrow;
            const int p = Mg_l & 7;
            if (p == 7) continue;
            const int bh_l = Mg_l >> 3;
            const int bhg = mb * 16 + bh_l;
            const int b = bhg / 7;
            const int h = bhg - 7 * b;
            #pragma unroll
            for (int nf = 0; nf < 4; ++nf) {
                const int i = i0 + wn * 64 + nf * 16 + ln15;
                out[(((size_t)b * 512 + i) * 7 + h) * 7 + p] = acc[mf][nf][r];
            }
        }
    }
}

extern "C" void kernel_launch(void* const* d_in, const int* in_sizes, int n_in,
                              void* d_out, int out_size, void* d_ws, size_t ws_size,
                              hipStream_t stream) {
    const float* x  = (const float*)d_in[0];   // (1024,512,7,7) fp32
    const float* Wg = (const float*)d_in[1];   // (256,3,3,512) fp32
    float* out = (float*)d_out;                // (1024,512,7,7) fp32
    __bf16* W2 = (__bf16*)d_ws;                // 512*2304 bf16 = 2.36 MB

    prep_w<<<dim3(192), dim3(256), 0, stream>>>(Wg, W2);

    if (ws_size >= WS_NEED) {
        __bf16* Vt = (__bf16*)((char*)d_ws + VT_OFFSET);
        prep_v<<<dim3(2048), dim3(256), 0, stream>>>(x, Vt);
        gemm_vt<<<dim3(448 * 4), dim3(256), 0, stream>>>(Vt, W2, out);
    } else {
        gemm_shift<<<dim3(448 * 4), dim3(256), 0, stream>>>(x, W2, out);
    }
}

// Round 4
// 358.360 us; speedup vs baseline: 1.4432x; 1.0852x over previous
//
#include <hip/hip_runtime.h>
#include <hip/hip_bf16.h>

// O[b,i,h,p] = sum_{c=l*3+j in 768, tap in 3} W[l,j,tap,i] * S_{b,h}[c][p+tap]
// S[c][t]: t=0,8,9 -> 0; t=(w+1)%7+1 <- V[c][w]
// V[c][w] = x[b,l,r1,w]*[0<=r1<7] + x[b,256+l,r2,w]*[0<=r2<7],
//   r1 = h+j-1, r2 = ((h+6)%7)+j-1            (verified rounds 1-2)
//
// Round 3: V precomputed into d_ws as Vt[bh][t][c] bf16 (77 MB).
// Round 4: prep_v LDS-staged/coalesced. Round 5: A-direct-global REFUTED.
// Round 6: prep_w tiled-transpose; total unchanged -> non-gemm ~200us is
//          either harness-fixed or a hidden prep pathology (top-5 saturated
//          by gemm_vt; can't see). Round 7: attack gemm_vt (LDS-pipe-bound:
//          127 LDS instrs/chunk/block + 3.5e7 conflict cyc = ~86% of time).
//          Both tiles now staged via global_load_lds (linear dest, source-
//          permuted swizzle), double-buffered, ONE barrier/chunk, 2-way-free
//          read banks. 127 -> 96 LDS instrs, zero ds_writes.

typedef __bf16 bf16x8 __attribute__((ext_vector_type(8)));
typedef float f32x4 __attribute__((ext_vector_type(4)));
typedef unsigned int u32;

#define VT_OFFSET (4u << 20)                       // W2 at d_ws+0, Vt at d_ws+4MB
#define VT_BYTES  (7168ull * 7 * 768 * 2)          // 77,070,336
#define WS_NEED   (VT_OFFSET + VT_BYTES)

__device__ __forceinline__ void gload_lds16(const void* g, void* l) {
    __builtin_amdgcn_global_load_lds(
        (const __attribute__((address_space(1))) u32*)g,
        (__attribute__((address_space(3))) u32*)l, 16, 0, 0);
}

// ---- prep_w: Wg[(c*3+tap)*512 + i] -> W2[i*2304 + tap*768 + c] ----
__global__ __launch_bounds__(256) void prep_w(const float* __restrict__ Wg,
                                              __bf16* __restrict__ W2) {
    __shared__ float ws_[96][65];                  // +1 pad
    const int kt = blockIdx.x % 24;
    const int it_ = blockIdx.x / 24;
    const int K0 = kt * 96;
    const int I0 = it_ * 64;
    const int tid = threadIdx.x;

    #pragma unroll
    for (int t = 0; t < 6; ++t) {
        const int u = t * 256 + tid;
        const int row = u >> 4;
        const int f4 = u & 15;
        const float4 v = *(const float4*)(Wg + (size_t)(K0 + row) * 512 + I0 + f4 * 4);
        ws_[row][f4 * 4 + 0] = v.x;
        ws_[row][f4 * 4 + 1] = v.y;
        ws_[row][f4 * 4 + 2] = v.z;
        ws_[row][f4 * 4 + 3] = v.w;
    }
    __syncthreads();

    #pragma unroll
    for (int t = 0; t < 3; ++t) {
        const int u = t * 256 + tid;
        const int i = u / 12;
        const int rem = u - i * 12;
        const int tap = rem >> 2;
        const int q = rem & 3;
        bf16x8 o;
        #pragma unroll
        for (int e = 0; e < 8; ++e) {
            const int c_loc = q * 8 + e;
            o[e] = (__bf16)ws_[3 * c_loc + tap][i];
        }
        *(bf16x8*)(W2 + (size_t)(I0 + i) * 2304 + tap * 768 + 32 * kt + q * 8) = o;
    }
}

// Block per (b, g) with g = channel-half.
__global__ __launch_bounds__(256) void prep_v(const float* __restrict__ x,
                                              __bf16* __restrict__ Vt) {
    __shared__ float xs[256 * 49];
    const int b = blockIdx.x >> 1;
    const int g = blockIdx.x & 1;
    const int tid = threadIdx.x;

    {
        const float4* src0 = (const float4*)(x + ((size_t)b * 512 + g * 128) * 49);
        const float4* src1 = (const float4*)(x + ((size_t)b * 512 + 256 + g * 128) * 49);
        float4* dst0 = (float4*)xs;
        float4* dst1 = (float4*)(xs + 128 * 49);
        #pragma unroll
        for (int it = 0; it < 7; ++it) {
            const int q = it * 256 + tid;
            if (q < 1568) dst0[q] = src0[q];
        }
        #pragma unroll
        for (int it = 0; it < 7; ++it) {
            const int q = it * 256 + tid;
            if (q < 1568) dst1[q] = src1[q];
        }
    }
    __syncthreads();

    for (int h = 0; h < 7; ++h) {
        const int hm = (h + 6) % 7;
        for (int it = 0; it < 2; ++it) {
            const int u = it * 256 + tid;
            if (u < 336) {
                const int r = u / 48;
                const int k = u - r * 48;
                const int w = (r + 6) % 7;
                bf16x8 vv;
                #pragma unroll
                for (int e = 0; e < 8; ++e) {
                    const int c = k * 8 + e;
                    const int l = c / 3;
                    const int j = c - 3 * l;
                    const int r1 = h + j - 1;
                    const int r2 = hm + j - 1;
                    float v = 0.f;
                    if (r1 >= 0 && r1 < 7) v += xs[l * 49 + r1 * 7 + w];
                    if (r2 >= 0 && r2 < 7) v += xs[(128 + l) * 49 + r2 * 7 + w];
                    vv[e] = (__bf16)v;
                }
                *(bf16x8*)(Vt + (size_t)((b * 7 + h) * 7 + r) * 768 + g * 384 + k * 8) = vv;
            }
        }
    }
}

// ---- gemm_vt v2: gload_lds double-buffered, 1 barrier/chunk ----
// LDS layout (bytes):
//   Tbuf0 [0,7168)      staged: bh*448 + ct*64 + slot*16   (ct = Vt row 0..6)
//   Z0    [7168,7232)   zeros (boundary taps)
//   Tbuf1 [7232,14400)  ; Z1 [14400,14464)
//   Bt0   [14464,39040) staged: tap*8192 + n*64 + slot*16
//   Bt1   [39040,63616)
// T read swizzle: slot = gq ^ (ct&3); Bt read swizzle: slot = gq ^ ((n>>1)&3).
// Staging puts source-q data at the matching slot by permuting the per-lane
// GLOBAL address (LDS dest stays lane-linear, as gload_lds requires).
__global__ __launch_bounds__(256) void gemm_vt(const __bf16* __restrict__ Vt,
                                               const __bf16* __restrict__ W2,
                                               float* __restrict__ out) {
    __shared__ __align__(1024) char L[63616];

    const int tid = threadIdx.x;
    const int g0 = blockIdx.x;
    const int nb = (g0 >> 3) & 3;
    const int mb = ((g0 >> 5) << 3) | (g0 & 7);    // 0..447
    const int i0 = nb * 128;

    // zero rows (one per T buffer), once
    if (tid < 32) {
        const int off = (tid < 16) ? 7168 + tid * 4 : 14400 + (tid - 16) * 4;
        *(int*)(L + off) = 0;
    }

    // ---- T-stage per-lane source offsets (448 units of 16B) ----
    int tsrc[2]; bool tok[2];
    #pragma unroll
    for (int it = 0; it < 2; ++it) {
        const int u = it * 256 + tid;
        tok[it] = (u < 448);
        const int bh = u / 28;
        const int rem = u - bh * 28;
        const int ct = rem >> 2;
        const int qs = rem & 3;
        const int q = qs ^ (ct & 3);               // slot qs holds source q
        tsrc[it] = ((mb * 16 + bh) * 7 + ct) * 1536 + q * 16;
    }
    // ---- Bt-stage per-lane source offsets (1536 units of 16B) ----
    int bsrc[6];
    #pragma unroll
    for (int it = 0; it < 6; ++it) {
        const int s = it * 256 + tid;
        const int tap = s >> 9;
        const int rem = s & 511;
        const int n = rem >> 2;
        const int qs = rem & 3;
        const int q = qs ^ ((n >> 1) & 3);
        bsrc[it] = ((i0 + n) * 2304 + tap * 768 + q * 8) * 2;
    }

    const int lane = tid & 63;
    const int wave = tid >> 6;
    const int wm = wave >> 1;
    const int wn = wave & 1;
    const int ln15 = lane & 15;
    const int gq = lane >> 4;

    // ---- chunk-invariant read offsets (relative to buffer base) ----
    int afoff[3][4], bfoff[3][4];
    #pragma unroll
    for (int tap = 0; tap < 3; ++tap) {
        #pragma unroll
        for (int mf = 0; mf < 4; ++mf) {
            const int bh_l = wm * 8 + mf * 2 + (ln15 >> 3);
            const int p = ln15 & 7;
            const int ct = p + tap - 1;
            afoff[tap][mf] = (ct >= 0 && ct <= 6)
                ? bh_l * 448 + ct * 64 + ((gq ^ (ct & 3)) * 16)
                : 7168;                            // zero row (broadcast)
        }
        #pragma unroll
        for (int nf = 0; nf < 4; ++nf) {
            const int n_l = wn * 64 + nf * 16 + ln15;
            bfoff[tap][nf] = tap * 8192 + n_l * 64 + ((gq ^ ((n_l >> 1) & 3)) * 16);
        }
    }

    f32x4 acc[4][4];
    #pragma unroll
    for (int a = 0; a < 4; ++a)
        #pragma unroll
        for (int bq = 0; bq < 4; ++bq) acc[a][bq] = (f32x4){0.f, 0.f, 0.f, 0.f};

    const char* VtB = (const char*)Vt;
    const char* W2B = (const char*)W2;

    // stage chunk ck into buffer buf
    auto stage = [&](int ck, int buf) {
        const char* vb = VtB + ck * 64;            // chunk*32 bf16
        char* td = L + buf * 7232;
        if (tok[0]) gload_lds16(vb + tsrc[0], td + tid * 16);
        if (tok[1]) gload_lds16(vb + tsrc[1], td + 4096 + tid * 16);
        const char* wb = W2B + ck * 64;
        char* bd = L + 14464 + buf * 24576;
        #pragma unroll
        for (int it = 0; it < 6; ++it)
            gload_lds16(wb + bsrc[it], bd + it * 4096 + tid * 16);
    };

    stage(0, 0);
    __syncthreads();                               // drains vmcnt: chunk-0 ready

    for (int chunk = 0; chunk < 24; ++chunk) {
        const int cur = chunk & 1;
        if (chunk < 23) stage(chunk + 1, cur ^ 1); // flies under the MFMAs

        const char* Tb = L + cur * 7232;
        const char* Bb = L + 14464 + cur * 24576;

        #pragma unroll
        for (int tap = 0; tap < 3; ++tap) {
            bf16x8 af[4], bfr[4];
            #pragma unroll
            for (int mf = 0; mf < 4; ++mf)
                af[mf] = *(const bf16x8*)(Tb + afoff[tap][mf]);
            #pragma unroll
            for (int nf = 0; nf < 4; ++nf)
                bfr[nf] = *(const bf16x8*)(Bb + bfoff[tap][nf]);
            #pragma unroll
            for (int mf = 0; mf < 4; ++mf)
                #pragma unroll
                for (int nf = 0; nf < 4; ++nf)
                    acc[mf][nf] = __builtin_amdgcn_mfma_f32_16x16x32_bf16(
                        af[mf], bfr[nf], acc[mf][nf], 0, 0, 0);
        }

        __syncthreads();       // all waves done with buf[cur]; prefetch landed
    }

    // ---- epilogue: D row = gq*4+r, col = lane&15 ----
    #pragma unroll
    for (int mf = 0; mf < 4; ++mf) {
        #pragma unroll
        for (int r = 0; r < 4; ++r) {
            const int mrow = gq * 4 + r;
            const int Mg_l = wm * 64 + mf * 16 + mrow;
            const int p = Mg_l & 7;
            if (p == 7) continue;                  // padded row
            const int bh_l = Mg_l >> 3;
            const int bhg = mb * 16 + bh_l;
            const int b = bhg / 7;
            const int h = bhg - 7 * b;
            #pragma unroll
            for (int nf = 0; nf < 4; ++nf) {
                const int i = i0 + wn * 64 + nf * 16 + ln15;
                out[(((size_t)b * 512 + i) * 7 + h) * 7 + p] = acc[mf][nf][r];
            }
        }
    }
}

// ---------------- fallback (round-2 implicit staging) if ws is small --------
__global__ __launch_bounds__(256) void gemm_shift(const float* __restrict__ x,
                                                  const __bf16* __restrict__ W2,
                                                  float* __restrict__ out) {
    __shared__ __bf16 T[16 * 10 * 40];
    __shared__ __bf16 Bt[128 * 104];

    const int tid = threadIdx.x;
    const int mb = blockIdx.x >> 2;
    const int nb = blockIdx.x & 3;
    const int i0 = nb * 128;

    const int cl  = tid & 31;
    const int bh0 = tid >> 5;
    const int bhg0 = mb * 16 + bh0;
    const int bhg1 = bhg0 + 8;
    const int b0 = bhg0 / 7, h0 = bhg0 - 7 * b0;
    const int b1 = bhg1 / 7, h1 = bhg1 - 7 * b1;
    const int hm0 = (h0 + 6) % 7, hm1 = (h1 + 6) % 7;

    for (int q = tid; q < 16 * 10 * 40 / 2; q += 256) ((int*)T)[q] = 0;

    const int lane = tid & 63;
    const int wave = tid >> 6;
    const int wm = wave >> 1;
    const int wn = wave & 1;
    const int ln15 = lane & 15;
    const int gq = lane >> 4;

    f32x4 acc[4][4];
    #pragma unroll
    for (int a = 0; a < 4; ++a)
        #pragma unroll
        for (int bq = 0; bq < 4; ++bq) acc[a][bq] = (f32x4){0.f, 0.f, 0.f, 0.f};

    __syncthreads();

    for (int chunk = 0; chunk < 24; ++chunk) {
        const int cg = chunk * 32 + cl;
        const int l = cg / 3;
        const int j = cg - 3 * l;
        {
            const int r1 = h0 + j - 1, r2 = hm0 + j - 1;
            float v[7] = {0.f, 0.f, 0.f, 0.f, 0.f, 0.f, 0.f};
            if (r1 >= 0 && r1 < 7) {
                const float* p1 = x + (((size_t)b0 * 512 + l) * 7 + r1) * 7;
                #pragma unroll
                for (int w = 0; w < 7; ++w) v[w] += p1[w];
            }
            if (r2 >= 0 && r2 < 7) {
                const float* p2 = x + (((size_t)b0 * 512 + 256 + l) * 7 + r2) * 7;
                #pragma unroll
                for (int w = 0; w < 7; ++w) v[w] += p2[w];
            }
            #pragma unroll
            for (int w = 0; w < 7; ++w)
                T[bh0 * 400 + ((w + 1) % 7 + 1) * 40 + cl] = (__bf16)v[w];
        }
        {
            const int r1 = h1 + j - 1, r2 = hm1 + j - 1;
            float v[7] = {0.f, 0.f, 0.f, 0.f, 0.f, 0.f, 0.f};
            if (r1 >= 0 && r1 < 7) {
                const float* p1 = x + (((size_t)b1 * 512 + l) * 7 + r1) * 7;
                #pragma unroll
                for (int w = 0; w < 7; ++w) v[w] += p1[w];
            }
            if (r2 >= 0 && r2 < 7) {
                const float* p2 = x + (((size_t)b1 * 512 + 256 + l) * 7 + r2) * 7;
                #pragma unroll
                for (int w = 0; w < 7; ++w) v[w] += p2[w];
            }
            #pragma unroll
            for (int w = 0; w < 7; ++w)
                T[(bh0 + 8) * 400 + ((w + 1) % 7 + 1) * 40 + cl] = (__bf16)v[w];
        }

        #pragma unroll
        for (int it = 0; it < 6; ++it) {
            const int u = it * 256 + tid;
            const int tap = u >> 9;
            const int rem = u & 511;
            const int n = rem >> 2;
            const int q = rem & 3;
            const float4 val = *(const float4*)(W2 + (size_t)(i0 + n) * 2304 +
                                                tap * 768 + chunk * 32 + q * 8);
            *(float4*)(&Bt[n * 104 + tap * 32 + q * 8]) = val;
        }

        __syncthreads();

        #pragma unroll
        for (int tap = 0; tap < 3; ++tap) {
            bf16x8 af[4], bfr[4];
            #pragma unroll
            for (int mf = 0; mf < 4; ++mf) {
                const int bh_l = wm * 8 + mf * 2 + (ln15 >> 3);
                const int p = ln15 & 7;
                af[mf] = *(const bf16x8*)(&T[(bh_l * 10 + p + tap) * 40 + gq * 8]);
            }
            #pragma unroll
            for (int nf = 0; nf < 4; ++nf) {
                const int n_l = wn * 64 + nf * 16 + ln15;
                bfr[nf] = *(const bf16x8*)(&Bt[n_l * 104 + tap * 32 + gq * 8]);
            }
            #pragma unroll
            for (int mf = 0; mf < 4; ++mf)
                #pragma unroll
                for (int nf = 0; nf < 4; ++nf)
                    acc[mf][nf] = __builtin_amdgcn_mfma_f32_16x16x32_bf16(
                        af[mf], bfr[nf], acc[mf][nf], 0, 0, 0);
        }

        __syncthreads();
    }

    #pragma unroll
    for (int mf = 0; mf < 4; ++mf) {
        #pragma unroll
        for (int r = 0; r < 4; ++r) {
            const int mrow = gq * 4 + r;
            const int Mg_l = wm * 64 + mf * 16 + mrow;
            const int p = Mg_l & 7;
            if (p == 7) continue;
            const int bh_l = Mg_l >> 3;
            const int bhg = mb * 16 + bh_l;
            const int b = bhg / 7;
            const int h = bhg - 7 * b;
            #pragma unroll
            for (int nf = 0; nf < 4; ++nf) {
                const int i = i0 + wn * 64 + nf * 16 + ln15;
                out[(((size_t)b * 512 + i) * 7 + h) * 7 + p] = acc[mf][nf][r];
            }
        }
    }
}

extern "C" void kernel_launch(void* const* d_in, const int* in_sizes, int n_in,
                              void* d_out, int out_size, void* d_ws, size_t ws_size,
                              hipStream_t stream) {
    const float* x  = (const float*)d_in[0];   // (1024,512,7,7) fp32
    const float* Wg = (const float*)d_in[1];   // (256,3,3,512) fp32
    float* out = (float*)d_out;                // (1024,512,7,7) fp32
    __bf16* W2 = (__bf16*)d_ws;                // 512*2304 bf16 = 2.36 MB

    prep_w<<<dim3(192), dim3(256), 0, stream>>>(Wg, W2);

    if (ws_size >= WS_NEED) {
        __bf16* Vt = (__bf16*)((char*)d_ws + VT_OFFSET);
        prep_v<<<dim3(2048), dim3(256), 0, stream>>>(x, Vt);
        gemm_vt<<<dim3(448 * 4), dim3(256), 0, stream>>>(Vt, W2, out);
    } else {
        gemm_shift<<<dim3(448 * 4), dim3(256), 0, stream>>>(x, W2, out);
    }
}